// Round 6
// baseline (243.623 us; speedup 1.0000x reference)
//
#include <hip/hip_runtime.h>
#include <hip/hip_bf16.h>
#include <stdint.h>

#define Hdim 512
#define KC   32768

typedef __hip_bfloat16 bf16;
typedef __attribute__((ext_vector_type(8))) short short8;
typedef __attribute__((ext_vector_type(4))) float float4v;

// pack two fp32 -> two bf16 (truncation) in one v_perm_b32
__device__ __forceinline__ unsigned int pack_bf16_trunc(float e0, float e1) {
  union { float f; unsigned int u; } a, b;
  a.f = e0; b.f = e1;
  return __builtin_amdgcn_perm(b.u, a.u, 0x07060302u);  // [hi16(e1):hi16(e0)]
}

__device__ __forceinline__ unsigned long long pack64(float4v v) {
  return (unsigned long long)pack_bf16_trunc(v[0], v[1])
       | ((unsigned long long)pack_bf16_trunc(v[2], v[3]) << 32);
}

// ---------------- launch 1: prep (blocks 0..31) + WT transpose (blocks 32..95) ----
// Block 0 additionally zeroes the fused-reduction accumulators + ticket counter
// (stream-ordered before the gemm launch, re-zeroed every rep/replay).
__global__ __launch_bounds__(256) void prep_wt_kernel(
    const float* __restrict__ input_, const float* __restrict__ h_0,
    const float* __restrict__ w_ih, const float* __restrict__ w_hh,
    const float* __restrict__ a_w_ih, const float* __restrict__ a_w_hh,
    float* __restrict__ gates, float* __restrict__ awi, bf16* __restrict__ wt,
    float* __restrict__ swg, float* __restrict__ swcg, int* __restrict__ counter) {
  __shared__ float sh[64 * 65];
  const int t = threadIdx.x;
  const int b = blockIdx.x;
  if (b == 0) {
    swg[t] = 0.f;  swg[256 + t] = 0.f;
    swcg[t] = 0.f; swcg[256 + t] = 0.f;
    if (t == 0) *counter = 0;
  }
  if (b < 32) {
    const int lane = t & 63, wv = t >> 6;
    float* h0s = sh;           // 512
    float* ins = sh + 512;     // 512
    float* red = sh + 1024;    // 256
    for (int i = t; i < 512; i += 256) { h0s[i] = h_0[i]; ins[i] = input_[i]; }
    __syncthreads();
    float acc = 0.f;
    if (b < 24) {
      const int j = b * 64 + lane;
      const float* whh = w_hh + j;
      const float* wih = w_ih + j;
#pragma unroll 16
      for (int i = 0; i < 128; ++i) {
        const int d = wv * 128 + i;
        acc += h0s[d] * whh[(size_t)d * 1536] + ins[d] * wih[(size_t)d * 1536];
      }
    } else {
      const int j = (b - 24) * 64 + lane;
      const float* wai = a_w_ih + j;
#pragma unroll 16
      for (int i = 0; i < 128; ++i) {
        const int d = wv * 128 + i;
        acc += ins[d] * wai[(size_t)d * Hdim];
      }
    }
    red[wv * 64 + lane] = acc;
    __syncthreads();
    if (t < 64) {
      float s = red[t] + red[64 + t] + red[128 + t] + red[192 + t];
      if (b < 24) gates[b * 64 + t] = s;
      else        awi[(b - 24) * 64 + t] = s;
    }
  } else {
    // WT[h][d] = bf16(a_w_hh[d][h])
    const int bb = b - 32;
    const int d0 = (bb & 7) * 64, h0 = (bb >> 3) * 64;
    const int tx = t & 63, tw = t >> 6;
    float (*tile)[65] = (float (*)[65])sh;
#pragma unroll
    for (int r = 0; r < 16; ++r) {
      const int row = r * 4 + tw;
      tile[row][tx] = a_w_hh[(size_t)(d0 + row) * Hdim + h0 + tx];
    }
    __syncthreads();
#pragma unroll
    for (int r = 0; r < 16; ++r) {
      const int row = r * 4 + tw;
      wt[(size_t)(h0 + row) * Hdim + d0 + tx] = __float2bfloat16(tile[tx][row]);
    }
  }
}

// ---------------- launch 2: fused GEMM + sigmoid/exp + reduction + finalize ----------------
// K-loop is byte-identical to the verified R3 structure (45.5us): 1024 blocks
// (XCD-swizzled), 256 threads (4 waves, 2x2), reg-staged A(f32->bf16 pack) and
// B(bf16) into double-buffered swizzled LDS, ONE barrier per K-iter, loads for
// t+1 issued before compute of t. Epilogue: per-block partials go through
// device-scope atomicAdd into swg/swcg[512]; the LAST block (ticket counter)
// re-reads totals L2-coherently and computes h1/c1 -> finalize launch removed.
__global__ __launch_bounds__(256) void gemm_reduce_kernel(
    const float* __restrict__ c_input, const bf16* __restrict__ WT,
    const float* __restrict__ awi,
    float* __restrict__ swg, float* __restrict__ swcg, int* __restrict__ counter,
    const float* __restrict__ gates, const float* __restrict__ bias,
    float* __restrict__ out) {
  __shared__ __align__(16) bf16 AsBuf[2][128 * 64];   // swizzled [row][g^(row&7)]
  __shared__ __align__(16) bf16 BsBuf[2][128 * 64];   // swizzled
  __shared__ float red_w[2][128];
  __shared__ float red_wc[2][128];
  __shared__ int ticket;

  const int tid  = threadIdx.x;
  const int lane = tid & 63;
  const int wave = tid >> 6;
  const int wm   = wave & 1;
  const int wn   = wave >> 1;
  const int lm   = lane & 15;
  const int lq   = lane >> 4;

  // XCD swizzle: the 4 h-blocks of one kk-slab share (id&7) -> same XCD, adjacent ids
  const int id     = blockIdx.x;
  const int kk_idx = ((id >> 5) << 3) | (id & 7);
  const int h_idx  = (id >> 3) & 3;
  const int kk0 = kk_idx * 128;
  const int h0  = h_idx * 128;

  char* const As0 = (char*)AsBuf[0];
  char* const As1 = (char*)AsBuf[1];
  char* const Bs0 = (char*)BsBuf[0];
  char* const Bs1 = (char*)BsBuf[1];

  // A staging geometry: thread owns 16B f32 chunk sub of rows j*16+rbase (j=0..7)
  const int sub   = tid & 15;
  const int rbase = tid >> 4;
  const float* aglobS = c_input + (size_t)(kk0 + rbase) * Hdim + sub * 4;
  const int a_lds = rbase * 128 + (((sub >> 1) ^ (rbase & 7)) * 16) + (sub & 1) * 8;

  // B staging geometry: rows r*32 + wave*8 + (lane>>3), granule g = lane&7
  const int brow0 = wave * 8 + (lane >> 3);
  const int bg    = lane & 7;
  const bf16* bglobS = WT + (size_t)(h0 + brow0) * Hdim + bg * 8;
  const int b_lds = brow0 * 128 + ((bg ^ (lane >> 3)) * 16);

  float4v acc[4][4];
#pragma unroll
  for (int i = 0; i < 4; ++i)
#pragma unroll
    for (int j = 0; j < 4; ++j)
      acc[i][j] = (float4v){0.f, 0.f, 0.f, 0.f};

  // ---- prologue: stage tile 0 into buf0 ----
  {
    float4v ap[8]; short8 bp[4];
#pragma unroll
    for (int j = 0; j < 8; ++j)
      ap[j] = *(const float4v*)(aglobS + j * 16 * Hdim);
#pragma unroll
    for (int r = 0; r < 4; ++r)
      bp[r] = *(const short8*)(bglobS + (size_t)r * 32 * Hdim);
#pragma unroll
    for (int j = 0; j < 8; ++j)
      *(unsigned long long*)(As0 + j * 2048 + a_lds) = pack64(ap[j]);
#pragma unroll
    for (int r = 0; r < 4; ++r)
      *(short8*)(Bs0 + r * 4096 + b_lds) = bp[r];
  }
  __syncthreads();

// one K-iteration: read RAs/RBs, prefetch tile T+1 into WAs/WBs (unless LAST)
#define GITER(T, RAs, RBs, WAs, WBs, NOT_LAST)                              \
  do {                                                                      \
    float4v ap[8]; short8 bp[4];                                            \
    if (NOT_LAST) {                                                         \
      const int dn = ((T) + 1) * 64;                                        \
      _Pragma("unroll")                                                     \
      for (int j = 0; j < 8; ++j)                                           \
        ap[j] = *(const float4v*)(aglobS + j * 16 * Hdim + dn);             \
      _Pragma("unroll")                                                     \
      for (int r = 0; r < 4; ++r)                                           \
        bp[r] = *(const short8*)(bglobS + (size_t)r * 32 * Hdim + dn);      \
    }                                                                       \
    __builtin_amdgcn_sched_barrier(0); /* pin load issue before compute */  \
    _Pragma("unroll")                                                       \
    for (int ks = 0; ks < 2; ++ks) {                                        \
      short8 a[4], bfr[4];                                                  \
      _Pragma("unroll")                                                     \
      for (int mt = 0; mt < 4; ++mt) {                                      \
        const int row = wm * 64 + mt * 16 + lm;                             \
        a[mt] = *(const short8*)(RAs + row * 128 +                          \
                                 (((ks * 4 + lq) ^ (lm & 7)) * 16));        \
      }                                                                     \
      _Pragma("unroll")                                                     \
      for (int nt = 0; nt < 4; ++nt) {                                      \
        const int row = wn * 64 + nt * 16 + lm;                             \
        bfr[nt] = *(const short8*)(RBs + row * 128 +                        \
                                   (((ks * 4 + lq) ^ (lm & 7)) * 16));      \
      }                                                                     \
      _Pragma("unroll")                                                     \
      for (int mt = 0; mt < 4; ++mt)                                        \
        _Pragma("unroll")                                                   \
        for (int nt = 0; nt < 4; ++nt)                                      \
          acc[mt][nt] = __builtin_amdgcn_mfma_f32_16x16x32_bf16(            \
              a[mt], bfr[nt], acc[mt][nt], 0, 0, 0);                        \
    }                                                                       \
    if (NOT_LAST) {                                                         \
      _Pragma("unroll")                                                     \
      for (int j = 0; j < 8; ++j)                                           \
        *(unsigned long long*)(WAs + j * 2048 + a_lds) = pack64(ap[j]);     \
      _Pragma("unroll")                                                     \
      for (int r = 0; r < 4; ++r)                                           \
        *(short8*)(WBs + r * 4096 + b_lds) = bp[r];                         \
    }                                                                       \
    __syncthreads();                                                        \
  } while (0)

  GITER(0, As0, Bs0, As1, Bs1, 1);
  GITER(1, As1, Bs1, As0, Bs0, 1);
  GITER(2, As0, Bs0, As1, Bs1, 1);
  GITER(3, As1, Bs1, As0, Bs0, 1);
  GITER(4, As0, Bs0, As1, Bs1, 1);
  GITER(5, As1, Bs1, As0, Bs0, 1);
  GITER(6, As0, Bs0, As1, Bs1, 1);
  GITER(7, As1, Bs1, As0, Bs0, 0);
#undef GITER

  // epilogue: alpha = sigmoid(acc + awi[h]); accumulate exp(alpha), exp(alpha)*c
  float awi_l[4];
#pragma unroll
  for (int nt = 0; nt < 4; ++nt)
    awi_l[nt] = awi[h0 + wn * 64 + nt * 16 + lm];

  float sw[4] = {0.f, 0.f, 0.f, 0.f}, swc[4] = {0.f, 0.f, 0.f, 0.f};
#pragma unroll
  for (int nt = 0; nt < 4; ++nt) {
    const int h = h0 + wn * 64 + nt * 16 + lm;
#pragma unroll
    for (int mt = 0; mt < 4; ++mt) {
      const int kkb = kk0 + wm * 64 + mt * 16 + lq * 4;
#pragma unroll
      for (int r = 0; r < 4; ++r) {
        float v = acc[mt][nt][r] + awi_l[nt];
        float aval = 1.f / (1.f + __expf(-v));
        float e = __expf(aval);
        float c = c_input[(size_t)(kkb + r) * Hdim + h];  // L2-hot after GEMM pass
        sw[nt]  += e;
        swc[nt] += e * c;
      }
    }
  }
#pragma unroll
  for (int nt = 0; nt < 4; ++nt) {
    sw[nt]  += __shfl_xor(sw[nt], 16, 64);
    sw[nt]  += __shfl_xor(sw[nt], 32, 64);
    swc[nt] += __shfl_xor(swc[nt], 16, 64);
    swc[nt] += __shfl_xor(swc[nt], 32, 64);
  }
  if (lq == 0) {
#pragma unroll
    for (int nt = 0; nt < 4; ++nt) {
      red_w[wm][wn * 64 + nt * 16 + lm]  = sw[nt];
      red_wc[wm][wn * 64 + nt * 16 + lm] = swc[nt];
    }
  }
  __syncthreads();
  // per-block partial -> device-scope accumulators (256 adders per address)
  if (tid < 128) {
    atomicAdd(&swg[h0 + tid],  red_w[0][tid] + red_w[1][tid]);
    atomicAdd(&swcg[h0 + tid], red_wc[0][tid] + red_wc[1][tid]);
  }
  __threadfence();          // order data atomics before the ticket
  __syncthreads();          // all 128 adders of this block done
  if (tid == 0) ticket = atomicAdd(counter, 1);
  __syncthreads();
  if (ticket == 1024 - 1) {
    // last block: totals are complete & visible at device scope
    for (int h = tid; h < Hdim; h += 256) {
      float swt  = atomicAdd(&swg[h], 0.f);    // L2-coherent read
      float swct = atomicAdd(&swcg[h], 0.f);
      float ipre = gates[h] + bias[h];
      float opre = gates[Hdim + h] + bias[Hdim + h];
      float gpre = gates[2 * Hdim + h] + bias[2 * Hdim + h];
      float ei = expf(1.f / (1.f + expf(-ipre)));   // exp(sigmoid(i))
      float g  = tanhf(gpre);
      float o  = 1.f / (1.f + expf(-opre));
      float denom = ei + swt + 1e-12f;
      float c1 = (ei * g + swct) / denom;
      float h1 = o * tanhf(c1);
      out[h]        = h1;
      out[Hdim + h] = c1;
    }
  }
}

extern "C" void kernel_launch(void* const* d_in, const int* in_sizes, int n_in,
                              void* d_out, int out_size, void* d_ws, size_t ws_size,
                              hipStream_t stream) {
  const float* input_  = (const float*)d_in[0];
  const float* c_input = (const float*)d_in[1];
  const float* h_0     = (const float*)d_in[2];
  /* d_in[3] = c_0: unused by the reference's taken branch */
  const float* w_ih    = (const float*)d_in[4];
  const float* w_hh    = (const float*)d_in[5];
  const float* bias    = (const float*)d_in[6];
  const float* a_w_ih  = (const float*)d_in[7];
  const float* a_w_hh  = (const float*)d_in[8];

  char* ws = (char*)d_ws;
  float* swg     = (float*)ws;                  // 2 KB
  float* swcg    = (float*)(ws + 2048);         // 2 KB
  int*   counter = (int*)(ws + 4096);           // 4 B (padded)
  float* gates   = (float*)(ws + 8192);         // 6 KB
  float* awi     = (float*)(ws + 8192 + 6144);  // 2 KB
  bf16*  WT      = (bf16*)(ws + 16384);         // 512 KB

  hipLaunchKernelGGL(prep_wt_kernel, dim3(96), dim3(256), 0, stream,
                     input_, h_0, w_ih, w_hh, a_w_ih, a_w_hh, gates, awi, WT,
                     swg, swcg, counter);
  hipLaunchKernelGGL(gemm_reduce_kernel, dim3(1024), dim3(256), 0, stream,
                     c_input, WT, awi, swg, swcg, counter, gates, bias,
                     (float*)d_out);
}

// Round 9
// 145.344 us; speedup vs baseline: 1.6762x; 1.6762x over previous
//
#include <hip/hip_runtime.h>
#include <hip/hip_bf16.h>
#include <stdint.h>

#define Hdim 512
#define KC   32768

typedef __hip_bfloat16 bf16;
typedef __attribute__((ext_vector_type(8))) short short8;
typedef __attribute__((ext_vector_type(4))) float float4v;

// pack two fp32 -> two bf16 (truncation) in one v_perm_b32
__device__ __forceinline__ unsigned int pack_bf16_trunc(float e0, float e1) {
  union { float f; unsigned int u; } a, b;
  a.f = e0; b.f = e1;
  return __builtin_amdgcn_perm(b.u, a.u, 0x07060302u);  // [hi16(e1):hi16(e0)]
}

__device__ __forceinline__ unsigned long long pack64(float4v v) {
  return (unsigned long long)pack_bf16_trunc(v[0], v[1])
       | ((unsigned long long)pack_bf16_trunc(v[2], v[3]) << 32);
}

// ---------------- launch 1: prep (blocks 0..31) + WT transpose (blocks 32..95) ----
__global__ __launch_bounds__(256) void prep_wt_kernel(
    const float* __restrict__ input_, const float* __restrict__ h_0,
    const float* __restrict__ w_ih, const float* __restrict__ w_hh,
    const float* __restrict__ a_w_ih, const float* __restrict__ a_w_hh,
    float* __restrict__ gates, float* __restrict__ awi, bf16* __restrict__ wt) {
  __shared__ float sh[64 * 65];
  const int t = threadIdx.x;
  const int b = blockIdx.x;
  if (b < 32) {
    const int lane = t & 63, wv = t >> 6;
    float* h0s = sh;           // 512
    float* ins = sh + 512;     // 512
    float* red = sh + 1024;    // 256
    for (int i = t; i < 512; i += 256) { h0s[i] = h_0[i]; ins[i] = input_[i]; }
    __syncthreads();
    float acc = 0.f;
    if (b < 24) {
      const int j = b * 64 + lane;
      const float* whh = w_hh + j;
      const float* wih = w_ih + j;
#pragma unroll 16
      for (int i = 0; i < 128; ++i) {
        const int d = wv * 128 + i;
        acc += h0s[d] * whh[(size_t)d * 1536] + ins[d] * wih[(size_t)d * 1536];
      }
    } else {
      const int j = (b - 24) * 64 + lane;
      const float* wai = a_w_ih + j;
#pragma unroll 16
      for (int i = 0; i < 128; ++i) {
        const int d = wv * 128 + i;
        acc += ins[d] * wai[(size_t)d * Hdim];
      }
    }
    red[wv * 64 + lane] = acc;
    __syncthreads();
    if (t < 64) {
      float s = red[t] + red[64 + t] + red[128 + t] + red[192 + t];
      if (b < 24) gates[b * 64 + t] = s;
      else        awi[(b - 24) * 64 + t] = s;
    }
  } else {
    // WT[h][d] = bf16(a_w_hh[d][h])
    const int bb = b - 32;
    const int d0 = (bb & 7) * 64, h0 = (bb >> 3) * 64;
    const int tx = t & 63, tw = t >> 6;
    float (*tile)[65] = (float (*)[65])sh;
#pragma unroll
    for (int r = 0; r < 16; ++r) {
      const int row = r * 4 + tw;
      tile[row][tx] = a_w_hh[(size_t)(d0 + row) * Hdim + h0 + tx];
    }
    __syncthreads();
#pragma unroll
    for (int r = 0; r < 16; ++r) {
      const int row = r * 4 + tw;
      wt[(size_t)(h0 + row) * Hdim + d0 + tx] = __float2bfloat16(tile[tx][row]);
    }
  }
}

// ---------------- launch 2: fused GEMM + sigmoid/exp + K-partial reduction ----------------
// R3-verified structure (45.5us) + two scheduling fixes:
//  (1) SECOND sched_barrier(0) after the MFMA cluster: R3's VGPR=100 proved the
//      compiler sank the pack/ds_writes (and their vmcnt wait) INTO the MFMA
//      cluster, draining the prefetch mid-phase. Pinning the writes after the
//      MFMAs keeps ap/bp live (VGPR should rise to ~140-165) and the global
//      latency hidden under the full compute phase.
//  (2) s_setprio(1) around the MFMA cluster (T5): the 4 blocks/CU are NOT
//      barrier-locked to each other -> cross-block phase diversity exists for
//      the CU scheduler to arbitrate (m224 regime, not m190's lockstep null).
__global__ __launch_bounds__(256) void gemm_reduce_kernel(
    const float* __restrict__ c_input, const bf16* __restrict__ WT,
    const float* __restrict__ awi,
    float* __restrict__ pw, float* __restrict__ pwc) {
  __shared__ __align__(16) bf16 AsBuf[2][128 * 64];   // swizzled [row][g^(row&7)]
  __shared__ __align__(16) bf16 BsBuf[2][128 * 64];   // swizzled
  __shared__ float red_w[2][128];
  __shared__ float red_wc[2][128];

  const int tid  = threadIdx.x;
  const int lane = tid & 63;
  const int wave = tid >> 6;
  const int wm   = wave & 1;
  const int wn   = wave >> 1;
  const int lm   = lane & 15;
  const int lq   = lane >> 4;

  // XCD swizzle: the 4 h-blocks of one kk-slab share (id&7) -> same XCD, adjacent ids
  const int id     = blockIdx.x;
  const int kk_idx = ((id >> 5) << 3) | (id & 7);
  const int h_idx  = (id >> 3) & 3;
  const int kk0 = kk_idx * 128;
  const int h0  = h_idx * 128;

  char* const As0 = (char*)AsBuf[0];
  char* const As1 = (char*)AsBuf[1];
  char* const Bs0 = (char*)BsBuf[0];
  char* const Bs1 = (char*)BsBuf[1];

  // A staging geometry: thread owns 16B f32 chunk sub of rows j*16+rbase (j=0..7)
  const int sub   = tid & 15;
  const int rbase = tid >> 4;
  const float* aglobS = c_input + (size_t)(kk0 + rbase) * Hdim + sub * 4;
  const int a_lds = rbase * 128 + (((sub >> 1) ^ (rbase & 7)) * 16) + (sub & 1) * 8;

  // B staging geometry: rows r*32 + wave*8 + (lane>>3), granule g = lane&7
  const int brow0 = wave * 8 + (lane >> 3);
  const int bg    = lane & 7;
  const bf16* bglobS = WT + (size_t)(h0 + brow0) * Hdim + bg * 8;
  const int b_lds = brow0 * 128 + ((bg ^ (lane >> 3)) * 16);

  float4v acc[4][4];
#pragma unroll
  for (int i = 0; i < 4; ++i)
#pragma unroll
    for (int j = 0; j < 4; ++j)
      acc[i][j] = (float4v){0.f, 0.f, 0.f, 0.f};

  // ---- prologue: stage tile 0 into buf0 ----
  {
    float4v ap[8]; short8 bp[4];
#pragma unroll
    for (int j = 0; j < 8; ++j)
      ap[j] = *(const float4v*)(aglobS + j * 16 * Hdim);
#pragma unroll
    for (int r = 0; r < 4; ++r)
      bp[r] = *(const short8*)(bglobS + (size_t)r * 32 * Hdim);
#pragma unroll
    for (int j = 0; j < 8; ++j)
      *(unsigned long long*)(As0 + j * 2048 + a_lds) = pack64(ap[j]);
#pragma unroll
    for (int r = 0; r < 4; ++r)
      *(short8*)(Bs0 + r * 4096 + b_lds) = bp[r];
  }
  __syncthreads();

// one K-iteration: read RAs/RBs, prefetch tile T+1 into WAs/WBs (unless LAST)
#define GITER(T, RAs, RBs, WAs, WBs, NOT_LAST)                              \
  do {                                                                      \
    float4v ap[8]; short8 bp[4];                                            \
    if (NOT_LAST) {                                                         \
      const int dn = ((T) + 1) * 64;                                        \
      _Pragma("unroll")                                                     \
      for (int j = 0; j < 8; ++j)                                           \
        ap[j] = *(const float4v*)(aglobS + j * 16 * Hdim + dn);             \
      _Pragma("unroll")                                                     \
      for (int r = 0; r < 4; ++r)                                           \
        bp[r] = *(const short8*)(bglobS + (size_t)r * 32 * Hdim + dn);      \
    }                                                                       \
    __builtin_amdgcn_sched_barrier(0); /* loads issue before compute */     \
    __builtin_amdgcn_s_setprio(1);                                          \
    _Pragma("unroll")                                                       \
    for (int ks = 0; ks < 2; ++ks) {                                        \
      short8 a[4], bfr[4];                                                  \
      _Pragma("unroll")                                                     \
      for (int mt = 0; mt < 4; ++mt) {                                      \
        const int row = wm * 64 + mt * 16 + lm;                             \
        a[mt] = *(const short8*)(RAs + row * 128 +                          \
                                 (((ks * 4 + lq) ^ (lm & 7)) * 16));        \
      }                                                                     \
      _Pragma("unroll")                                                     \
      for (int nt = 0; nt < 4; ++nt) {                                      \
        const int row = wn * 64 + nt * 16 + lm;                             \
        bfr[nt] = *(const short8*)(RBs + row * 128 +                        \
                                   (((ks * 4 + lq) ^ (lm & 7)) * 16));      \
      }                                                                     \
      _Pragma("unroll")                                                     \
      for (int mt = 0; mt < 4; ++mt)                                        \
        _Pragma("unroll")                                                   \
        for (int nt = 0; nt < 4; ++nt)                                      \
          acc[mt][nt] = __builtin_amdgcn_mfma_f32_16x16x32_bf16(            \
              a[mt], bfr[nt], acc[mt][nt], 0, 0, 0);                        \
    }                                                                       \
    __builtin_amdgcn_s_setprio(0);                                          \
    __builtin_amdgcn_sched_barrier(0); /* writes (and vmcnt wait) AFTER */  \
    if (NOT_LAST) {                                                         \
      _Pragma("unroll")                                                     \
      for (int j = 0; j < 8; ++j)                                           \
        *(unsigned long long*)(WAs + j * 2048 + a_lds) = pack64(ap[j]);     \
      _Pragma("unroll")                                                     \
      for (int r = 0; r < 4; ++r)                                           \
        *(short8*)(WBs + r * 4096 + b_lds) = bp[r];                         \
    }                                                                       \
    __syncthreads();                                                        \
  } while (0)

  GITER(0, As0, Bs0, As1, Bs1, 1);
  GITER(1, As1, Bs1, As0, Bs0, 1);
  GITER(2, As0, Bs0, As1, Bs1, 1);
  GITER(3, As1, Bs1, As0, Bs0, 1);
  GITER(4, As0, Bs0, As1, Bs1, 1);
  GITER(5, As1, Bs1, As0, Bs0, 1);
  GITER(6, As0, Bs0, As1, Bs1, 1);
  GITER(7, As1, Bs1, As0, Bs0, 0);
#undef GITER

  // epilogue: alpha = sigmoid(acc + awi[h]); accumulate exp(alpha), exp(alpha)*c
  float awi_l[4];
#pragma unroll
  for (int nt = 0; nt < 4; ++nt)
    awi_l[nt] = awi[h0 + wn * 64 + nt * 16 + lm];

  float sw[4] = {0.f, 0.f, 0.f, 0.f}, swc[4] = {0.f, 0.f, 0.f, 0.f};
#pragma unroll
  for (int nt = 0; nt < 4; ++nt) {
    const int h = h0 + wn * 64 + nt * 16 + lm;
#pragma unroll
    for (int mt = 0; mt < 4; ++mt) {
      const int kkb = kk0 + wm * 64 + mt * 16 + lq * 4;
#pragma unroll
      for (int r = 0; r < 4; ++r) {
        float v = acc[mt][nt][r] + awi_l[nt];
        float aval = 1.f / (1.f + __expf(-v));
        float e = __expf(aval);
        float c = c_input[(size_t)(kkb + r) * Hdim + h];  // L2-hot after GEMM pass
        sw[nt]  += e;
        swc[nt] += e * c;
      }
    }
  }
#pragma unroll
  for (int nt = 0; nt < 4; ++nt) {
    sw[nt]  += __shfl_xor(sw[nt], 16, 64);
    sw[nt]  += __shfl_xor(sw[nt], 32, 64);
    swc[nt] += __shfl_xor(swc[nt], 16, 64);
    swc[nt] += __shfl_xor(swc[nt], 32, 64);
  }
  if (lq == 0) {
#pragma unroll
    for (int nt = 0; nt < 4; ++nt) {
      red_w[wm][wn * 64 + nt * 16 + lm]  = sw[nt];
      red_wc[wm][wn * 64 + nt * 16 + lm] = swc[nt];
    }
  }
  __syncthreads();
  if (tid < 128) {
    pw[(size_t)kk_idx * Hdim + h0 + tid]  = red_w[0][tid] + red_w[1][tid];
    pwc[(size_t)kk_idx * Hdim + h0 + tid] = red_wc[0][tid] + red_wc[1][tid];
  }
}

// ---------------- launch 3: final reduction + LSTM merge ----------------
__global__ __launch_bounds__(256) void finalize_kernel(
    const float* __restrict__ pw, const float* __restrict__ pwc,
    const float* __restrict__ gates, const float* __restrict__ bias,
    float* __restrict__ out) {
  __shared__ float rsw[8][32], rswc[8][32];
  const int t = threadIdx.x;
  const int hl = t & 31, q = t >> 5;
  const int hh = blockIdx.x * 32 + hl;
  float sw = 0.f, swc = 0.f;
#pragma unroll 8
  for (int kb = q * 32; kb < q * 32 + 32; ++kb) {
    sw  += pw[(size_t)kb * Hdim + hh];
    swc += pwc[(size_t)kb * Hdim + hh];
  }
  rsw[q][hl] = sw; rswc[q][hl] = swc;
  __syncthreads();
  if (t < 32) {
    const int h = blockIdx.x * 32 + t;
    sw = 0.f; swc = 0.f;
#pragma unroll
    for (int q2 = 0; q2 < 8; ++q2) { sw += rsw[q2][t]; swc += rswc[q2][t]; }
    float ipre = gates[h] + bias[h];
    float opre = gates[Hdim + h] + bias[Hdim + h];
    float gpre = gates[2 * Hdim + h] + bias[2 * Hdim + h];
    float ei = expf(1.f / (1.f + expf(-ipre)));   // exp(sigmoid(i))
    float g  = tanhf(gpre);
    float o  = 1.f / (1.f + expf(-opre));
    float denom = ei + sw + 1e-12f;
    float c1 = (ei * g + swc) / denom;
    float h1 = o * tanhf(c1);
    out[h]        = h1;
    out[Hdim + h] = c1;
  }
}

extern "C" void kernel_launch(void* const* d_in, const int* in_sizes, int n_in,
                              void* d_out, int out_size, void* d_ws, size_t ws_size,
                              hipStream_t stream) {
  const float* input_  = (const float*)d_in[0];
  const float* c_input = (const float*)d_in[1];
  const float* h_0     = (const float*)d_in[2];
  /* d_in[3] = c_0: unused by the reference's taken branch */
  const float* w_ih    = (const float*)d_in[4];
  const float* w_hh    = (const float*)d_in[5];
  const float* bias    = (const float*)d_in[6];
  const float* a_w_ih  = (const float*)d_in[7];
  const float* a_w_hh  = (const float*)d_in[8];

  char* ws = (char*)d_ws;
  float* pw    = (float*)ws;                          // 256*512 f32 = 512 KB
  float* pwc   = (float*)(ws + 512 * 1024);           // 512 KB
  float* gates = (float*)(ws + 1024 * 1024);          // 6 KB
  float* awi   = (float*)(ws + 1024 * 1024 + 6144);   // 2 KB
  bf16*  WT    = (bf16*)(ws + 1024 * 1024 + 8192);    // 512 KB

  hipLaunchKernelGGL(prep_wt_kernel, dim3(96), dim3(256), 0, stream,
                     input_, h_0, w_ih, w_hh, a_w_ih, a_w_hh, gates, awi, WT);
  hipLaunchKernelGGL(gemm_reduce_kernel, dim3(1024), dim3(256), 0, stream,
                     c_input, WT, awi, pw, pwc);
  hipLaunchKernelGGL(finalize_kernel, dim3(8 * 2), dim3(256), 0, stream,
                     pw, pwc, gates, bias, (float*)d_out);
}